// Round 11
// baseline (123.318 us; speedup 1.0000x reference)
//
#include <hip/hip_runtime.h>

// VQEmbedding: B=32,T=1024,D=256,K=1024. N=32768 rows.
// Exact score (proven r2-r10): s = fl32( fl32(csqr_k + xsqr_i) - 2*dot_ik ), argmin,
// first-index ties via packed u64 keys. bf16 MFMA approx (fragment layout verified
// r4-r10); two-pass margin filter; exact fp32 rescore (r2 chain).
// r11 change (r9/r10 invariant: ~3.2K cy/chunk with all pipes <20% = barrier-per-chunk
// stall at 2 waves/SIMD, NOT LDS bandwidth):
//  - ZERO barriers in the main loop: wave owns all 64 rows x a PRIVATE code quarter;
//    margin threshold is wave-LOCAL (sound: a(k*) <= global_min+2eps <= local_min+2eps,
//    since local_min >= global_min; all exact ties captured likewise).
//  - B-fragments read directly from L2 (no LDS staging): 64-row reuse cuts private
//    traffic to 512MB (~15us aggregate) — fixes what made r6's direct reads slow.
//  - register double-buffer for B (bvA/bvB, MLP=8, r5 lesson); VGPR cap 256 (no spill).

#define NROWS  32768
#define DDIM   256
#define KCODES 1024
#define MARGIN 1.5e-3f
#define CAP    1024
#define RPB    64          // rows per block = rows per wave (4 A-tiles of 16)

typedef __attribute__((ext_vector_type(8))) short short8;
typedef __attribute__((ext_vector_type(4))) float f32x4;

__device__ __forceinline__ unsigned short f2bf(float f) {   // RNE f32->bf16
    unsigned u = __float_as_uint(f);
    return (unsigned short)((u + 0x7FFFu + ((u >> 16) & 1u)) >> 16);
}

// exact fp32 dot — BIT-IDENTICAL chain to r2-r10 (proven). DO NOT reorder.
__device__ __forceinline__ float exact_dot(const float* __restrict__ xrow,
                                           const float* __restrict__ crow) {
    const float4* xp = (const float4*)xrow;
    const float4* cp = (const float4*)crow;
    float A = 0.f, B = 0.f;
    #pragma unroll 8
    for (int d4 = 0; d4 < 32; ++d4) {
        float4 xv = xp[d4], cv = cp[d4];
        A = __fmaf_rn(xv.x, cv.x, A);
        A = __fmaf_rn(xv.y, cv.y, A);
        A = __fmaf_rn(xv.z, cv.z, A);
        A = __fmaf_rn(xv.w, cv.w, A);
    }
    #pragma unroll 8
    for (int d4 = 32; d4 < 64; ++d4) {
        float4 xv = xp[d4], cv = cp[d4];
        B = __fmaf_rn(xv.x, cv.x, B);
        B = __fmaf_rn(xv.y, cv.y, B);
        B = __fmaf_rn(xv.z, cv.z, B);
        B = __fmaf_rn(xv.w, cv.w, B);
    }
    return __fadd_rn(A, B);
}

// --- csqr[k] (proven r2-r10, unchanged) ---
__global__ __launch_bounds__(256) void vq_csqr(const float* __restrict__ cb,
                                               float* __restrict__ csqr) {
    int gid  = blockIdx.x * 256 + threadIdx.x;
    int w    = gid >> 6;
    int lane = threadIdx.x & 63;
    if (w >= KCODES) return;
    float4 v = reinterpret_cast<const float4*>(cb)[w * (DDIM / 4) + lane];
    float s = v.x * v.x + v.y * v.y + v.z * v.z + v.w * v.w;
    #pragma unroll
    for (int off = 32; off > 0; off >>= 1) s += __shfl_down(s, off, 64);
    if (lane == 0) csqr[w] = s;
}

// --- xsqr[r] (proven r3-r10, unchanged) ---
__global__ __launch_bounds__(256) void vq_xsqr(const float* __restrict__ x,
                                               float* __restrict__ xsqr) {
    int w = threadIdx.x >> 6, lane = threadIdx.x & 63;
    int row = blockIdx.x * 4 + w;
    float4 v = reinterpret_cast<const float4*>(x + (size_t)row * DDIM)[lane];
    float s = v.x * v.x + v.y * v.y + v.z * v.z + v.w * v.w;
    #pragma unroll
    for (int off = 32; off > 0; off >>= 1) s += __shfl_down(s, off, 64);
    if (lane == 0) xsqr[row] = s;
}

// --- cb -> bf16 B-fragments (layout verified r4-r10): frag(nt,ks): lane l elem i =
//     cb[nt*16 + (l&15)][ks*32 + (l>>4)*8 + i]; linear id = (nt*8+ks)*64 + l ---
__global__ __launch_bounds__(256) void vq_cbfrag(const float* __restrict__ cb,
                                                 short* __restrict__ cbh) {
    int id   = blockIdx.x * 256 + threadIdx.x;
    int lane = id & 63;
    int ks   = (id >> 6) & 7;
    int nt   = id >> 9;
    int code = nt * 16 + (lane & 15);
    int d0   = ks * 32 + (lane >> 4) * 8;
    const float4* p = (const float4*)(cb + (size_t)code * DDIM + d0);
    float4 a = p[0], b = p[1];
    short8 v;
    v[0] = (short)f2bf(a.x); v[1] = (short)f2bf(a.y);
    v[2] = (short)f2bf(a.z); v[3] = (short)f2bf(a.w);
    v[4] = (short)f2bf(b.x); v[5] = (short)f2bf(b.y);
    v[6] = (short)f2bf(b.z); v[7] = (short)f2bf(b.w);
    *(short8*)(cbh + (size_t)id * 8) = v;
}

// --- main: 64 rows/block; wave w privately covers codes w*256..+256; no main-loop
//     barriers; B double-buffered in registers straight from L2. ---
__global__ __launch_bounds__(256, 2) void vq_main(const float* __restrict__ x,
                                                  const float* __restrict__ cb,
                                                  const short* __restrict__ cbh,
                                                  const float* __restrict__ csqr,
                                                  const float* __restrict__ xsqr,
                                                  float* __restrict__ out) {
    __shared__ float              csl[KCODES];   // 4KB
    __shared__ unsigned long long keys[RPB];
    __shared__ unsigned           list[CAP];
    __shared__ int                fidx[RPB];
    __shared__ int                cnt, ovf;

    const int t    = threadIdx.x;
    const int lane = t & 63;
    const int w    = t >> 6;         // 0..3 (wave = private code quarter)
    const int r0   = blockIdx.x * RPB;
    const int lr   = lane & 15;
    const int lg   = lane >> 4;

    ((float4*)csl)[t] = ((const float4*)csqr)[t];
    if (t < RPB) keys[t] = ~0ULL;
    if (t == 0) { cnt = 0; ovf = 0; }
    __syncthreads();                 // csl/keys/cnt ready (only pre-loop barrier)

    // A-fragments for ALL 64 rows (4 tiles of 16). Mapping identical to r4-r10.
    short8 afr[4][8];
    #pragma unroll
    for (int tile = 0; tile < 4; ++tile) {
        const float* xr = x + (size_t)(r0 + tile * 16 + lr) * DDIM;
        #pragma unroll
        for (int ks = 0; ks < 8; ++ks) {
            float4 a = *(const float4*)&xr[ks * 32 + lg * 8];
            float4 b = *(const float4*)&xr[ks * 32 + lg * 8 + 4];
            short8 v;
            v[0] = (short)f2bf(a.x); v[1] = (short)f2bf(a.y);
            v[2] = (short)f2bf(a.z); v[3] = (short)f2bf(a.w);
            v[4] = (short)f2bf(b.x); v[5] = (short)f2bf(b.y);
            v[6] = (short)f2bf(b.z); v[7] = (short)f2bf(b.w);
            afr[tile][ks] = v;
        }
    }

    const short8* cbh8 = (const short8*)cbh;

    // load B-fragment tile c (of my quarter) into a named register buffer
    auto load_bv = [&](short8 (&bv)[8], int c) {
        const short8* bp = cbh8 + (size_t)((w * 16 + c) * 8) * 64 + lane;
        #pragma unroll
        for (int ks = 0; ks < 8; ++ks) bv[ks] = bp[(size_t)ks * 64];
    };
    // 16x16 scores for tile c; PASS1: running min. PASS2: candidate append.
    float runp[4][4];
    #pragma unroll
    for (int tile = 0; tile < 4; ++tile)
        #pragma unroll
        for (int j = 0; j < 4; ++j) runp[tile][j] = __builtin_inff();
    float thr[4][4];

    auto chunk = [&](const short8 (&bv)[8], int c, int pass) {
        f32x4 af[4];
        #pragma unroll
        for (int tile = 0; tile < 4; ++tile) af[tile] = (f32x4){0.f, 0.f, 0.f, 0.f};
        #pragma unroll
        for (int ks = 0; ks < 8; ++ks) {
            #pragma unroll
            for (int tile = 0; tile < 4; ++tile)
                af[tile] = __builtin_amdgcn_mfma_f32_16x16x32_bf16(afr[tile][ks], bv[ks], af[tile], 0, 0, 0);
        }
        const int code = (w * 16 + c) * 16 + lr;
        const float cs1 = __fadd_rn(csl[code], 1.0f);   // +1: score>0 (bit order = float order)
        if (pass == 1) {
            #pragma unroll
            for (int tile = 0; tile < 4; ++tile)
                #pragma unroll
                for (int j = 0; j < 4; ++j)
                    runp[tile][j] = fminf(runp[tile][j], __fmaf_rn(-2.f, af[tile][j], cs1));
        } else {
            #pragma unroll
            for (int tile = 0; tile < 4; ++tile)
                #pragma unroll
                for (int j = 0; j < 4; ++j) {
                    float s = __fmaf_rn(-2.f, af[tile][j], cs1);   // bit-identical recompute
                    if (s <= thr[tile][j]) {
                        int row = tile * 16 + lg * 4 + j;
                        int pos = atomicAdd(&cnt, 1);
                        if (pos < CAP) list[pos] = ((unsigned)row << 10) | (unsigned)code;
                        else ovf = 1;
                    }
                }
        }
    };

    short8 bvA[8], bvB[8];
    // ---- pass 1 (reg double-buffer, no barriers) ----
    load_bv(bvA, 0);
    for (int cp = 0; cp < 8; ++cp) {
        load_bv(bvB, 2 * cp + 1);
        chunk(bvA, 2 * cp, 1);
        if (cp < 7) load_bv(bvA, 2 * cp + 2);
        chunk(bvB, 2 * cp + 1, 1);
    }
    // wave-LOCAL threshold: butterfly over the 16 lr lanes only (sound; see header)
    #pragma unroll
    for (int tile = 0; tile < 4; ++tile)
        #pragma unroll
        for (int j = 0; j < 4; ++j) {
            float v = runp[tile][j];
            v = fminf(v, __shfl_xor(v, 1, 64));
            v = fminf(v, __shfl_xor(v, 2, 64));
            v = fminf(v, __shfl_xor(v, 4, 64));
            v = fminf(v, __shfl_xor(v, 8, 64));
            thr[tile][j] = v + MARGIN;
        }
    // ---- pass 2 (bit-identical recompute, candidate append) ----
    load_bv(bvA, 0);
    for (int cp = 0; cp < 8; ++cp) {
        load_bv(bvB, 2 * cp + 1);
        chunk(bvA, 2 * cp, 2);
        if (cp < 7) load_bv(bvA, 2 * cp + 2);
        chunk(bvB, 2 * cp + 1, 2);
    }
    __syncthreads();   // all waves' candidates in list

    // ---- exact rescore (r2-proven chain + grid formula), u64 first-index argmin ----
    if (ovf || cnt > CAP) {
        for (int it = t; it < RPB * KCODES; it += 256) {   // safety net (never fires)
            int row = it >> 10, code = it & (KCODES - 1);
            float dot = exact_dot(x + (size_t)(r0 + row) * DDIM, cb + (size_t)code * DDIM);
            float s   = __fmaf_rn(-2.f, dot, __fadd_rn(csl[code], xsqr[r0 + row]));
            atomicMin(&keys[row], ((unsigned long long)__float_as_uint(s) << 32) | (unsigned)code);
        }
    } else {
        for (int i = t; i < cnt; i += 256) {
            unsigned e = list[i];
            int row = (int)(e >> 10), code = (int)(e & 0x3FFu);
            float dot = exact_dot(x + (size_t)(r0 + row) * DDIM, cb + (size_t)code * DDIM);
            float s   = __fmaf_rn(-2.f, dot, __fadd_rn(csl[code], xsqr[r0 + row]));
            atomicMin(&keys[row], ((unsigned long long)__float_as_uint(s) << 32) | (unsigned)code);
        }
    }
    __syncthreads();

    if (t < RPB) {
        int code = (int)(unsigned)(keys[t] & 0xffffffffu);
        fidx[t] = code;
        out[(size_t)2 * NROWS * DDIM + (r0 + t)] = (float)code;
    }
    __syncthreads();

    // gather winning codes: 64 rows x 64 float4, coalesced
    const float4* cb4  = (const float4*)cb;
    float4*       out0 = (float4*)out;
    float4*       out1 = out0 + (size_t)NROWS * (DDIM / 4);
    #pragma unroll
    for (int i = 0; i < 16; ++i) {
        int it  = i * 256 + t;
        int row = it >> 6, col = it & 63;
        float4 v = cb4[(size_t)fidx[row] * (DDIM / 4) + col];
        size_t o = (size_t)(r0 + row) * (DDIM / 4) + col;
        out0[o] = v;
        out1[o] = v;
    }
}

extern "C" void kernel_launch(void* const* d_in, const int* in_sizes, int n_in,
                              void* d_out, int out_size, void* d_ws, size_t ws_size,
                              hipStream_t stream) {
    const float* x   = (const float*)d_in[0];   // z_e_x   [32768,256]
    const float* cb  = (const float*)d_in[1];   // codebook [1024,256]
    float*       out = (float*)d_out;

    float* ws_csqr = (float*)d_ws;                // [1024]
    float* ws_xsqr = ws_csqr + KCODES;            // [32768]
    short* ws_cbh  = (short*)(ws_xsqr + NROWS);   // [1024*256] bf16 frags

    vq_cbfrag<<<128,        256, 0, stream>>>(cb, ws_cbh);
    vq_csqr  <<<256,        256, 0, stream>>>(cb, ws_csqr);
    vq_xsqr  <<<NROWS / 4,  256, 0, stream>>>(x, ws_xsqr);
    vq_main  <<<NROWS / RPB, 256, 0, stream>>>(x, cb, ws_cbh, ws_csqr, ws_xsqr, out);
}